// Round 1
// 353.093 us; speedup vs baseline: 1.4102x; 1.4102x over previous
//
#include <hip/hip_runtime.h>

__device__ __forceinline__ float2 cmul(float2 a, float2 b) {
    return make_float2(a.x*b.x - a.y*b.y, a.x*b.y + a.y*b.x);
}
__device__ __forceinline__ float2 cadd(float2 a, float2 b){ return make_float2(a.x+b.x, a.y+b.y); }
__device__ __forceinline__ float2 csub(float2 a, float2 b){ return make_float2(a.x-b.x, a.y-b.y); }

// multiply by (0, SGN): forward SGN=-1, inverse SGN=+1
template<int SGN> __device__ __forceinline__ float2 mul_i(float2 a) {
    return (SGN > 0) ? make_float2(-a.y, a.x) : make_float2(a.y, -a.x);
}
// W8^1 = (r, SGN*r), r = sqrt(0.5)
template<int SGN> __device__ __forceinline__ float2 mul_w81(float2 a) {
    const float r = 0.70710678118654752440f;
    return (SGN > 0) ? make_float2(r*(a.x - a.y), r*(a.x + a.y))
                     : make_float2(r*(a.x + a.y), r*(a.y - a.x));
}
// W8^3 = (-r, SGN*r)
template<int SGN> __device__ __forceinline__ float2 mul_w83(float2 a) {
    const float r = 0.70710678118654752440f;
    return (SGN > 0) ? make_float2(-r*(a.x + a.y), r*(a.x - a.y))
                     : make_float2(r*(a.y - a.x), -r*(a.x + a.y));
}

// 8-point DFT in registers, natural-order output: out[q] = sum_k in[k] W8^{SGN*qk}
template<int SGN>
__device__ __forceinline__ void bfly8(float2 v[8]) {
    float2 s0 = cadd(v[0], v[4]), d0 = csub(v[0], v[4]);
    float2 s1 = cadd(v[1], v[5]), d1 = csub(v[1], v[5]);
    float2 s2 = cadd(v[2], v[6]), d2 = csub(v[2], v[6]);
    float2 s3 = cadd(v[3], v[7]), d3 = csub(v[3], v[7]);
    d1 = mul_w81<SGN>(d1);
    d2 = mul_i<SGN>(d2);
    d3 = mul_w83<SGN>(d3);
    float2 p0 = cadd(s0, s2), q0 = csub(s0, s2);
    float2 p1 = cadd(s1, s3), q1 = mul_i<SGN>(csub(s1, s3));
    float2 P0 = cadd(d0, d2), Q0 = csub(d0, d2);
    float2 P1 = cadd(d1, d3), Q1 = mul_i<SGN>(csub(d1, d3));
    v[0] = cadd(p0, p1);
    v[4] = csub(p0, p1);
    v[2] = cadd(q0, q1);
    v[6] = csub(q0, q1);
    v[1] = cadd(P0, P1);
    v[5] = csub(P0, P1);
    v[3] = cadd(Q0, Q1);
    v[7] = csub(Q0, Q1);
}

// v[q] *= W^{SGN*q}, W = cis(2*pi*frac)
template<int SGN>
__device__ __forceinline__ void twiddle7(float2 v[8], float frac) {
    const float ang = (SGN > 0 ? 6.2831853071795864769f : -6.2831853071795864769f) * frac;
    float sn, cs; __sincosf(ang, &sn, &cs);
    const float2 w1 = make_float2(cs, sn);
    float2 w = w1;
    v[1] = cmul(v[1], w);
#pragma unroll
    for (int q = 2; q < 8; ++q) { w = cmul(w, w1); v[q] = cmul(v[q], w); }
}

// Swizzles for the two LDS exchanges (both uniform 4 accesses/bank for b64):
//   f1(a) = a + 2*(a>>6)  (exchange stride-64 <-> stride-8 pattern)
//   f2(a) = a + (a>>3)    (exchange stride-8  <-> contiguous pattern)

// Forward 512-pt FFT, one wave, lane l (0..63), v preloaded with h = l+64k.
// Output: v[q] = spectrum value at position p = 8l+q (freq = octal-digit-rev(p)).
// S: per-wave scratch, >= 575 float2. Uses 2 block barriers.
__device__ __forceinline__ void fft512_fwd(float2 v[8], float2* S, int l) {
    const int g = l >> 3, j = l & 7;
    bfly8<-1>(v);
    twiddle7<-1>(v, (float)l * (1.0f/512.0f));
#pragma unroll
    for (int q = 0; q < 8; ++q) S[66*q + l] = v[q];          // f1(64q+l)
    __syncthreads();
#pragma unroll
    for (int k = 0; k < 8; ++k) v[k] = S[66*g + j + 8*k];    // f1(64g+j+8k)
    bfly8<-1>(v);
    twiddle7<-1>(v, (float)j * (1.0f/64.0f));
#pragma unroll
    for (int q = 0; q < 8; ++q) S[72*g + 9*q + j] = v[q];    // f2(64g+8q+j)
    __syncthreads();
#pragma unroll
    for (int k = 0; k < 8; ++k) v[k] = S[9*l + k];           // f2(8l+k)
    bfly8<-1>(v);
}

// Inverse (unscaled, x512): input v[q] = value at position 8l+q, output
// v[k] = natural-order sample at h = l+64k. Exact mirror of fft512_fwd.
__device__ __forceinline__ void fft512_inv(float2 v[8], float2* S, int l) {
    const int g = l >> 3, j = l & 7;
    bfly8<1>(v);
#pragma unroll
    for (int k = 0; k < 8; ++k) S[9*l + k] = v[k];
    __syncthreads();
#pragma unroll
    for (int q = 0; q < 8; ++q) v[q] = S[72*g + 9*q + j];
    twiddle7<1>(v, (float)j * (1.0f/64.0f));
    bfly8<1>(v);
#pragma unroll
    for (int k = 0; k < 8; ++k) S[66*g + j + 8*k] = v[k];
    __syncthreads();
#pragma unroll
    for (int q = 0; q < 8; ++q) v[q] = S[66*q + l];
    twiddle7<1>(v, (float)l * (1.0f/512.0f));
    bfly8<1>(v);
}

__device__ __forceinline__ int drev(int x) {   // reverse 3 octal digits of 9-bit x
    return ((x & 7) << 6) | (x & 56) | (x >> 6);
}

// Prologue: Hp[pw*512 + ph] = Hh[drev(ph)][drev(pw)] where Hh is the
// HERMITIAN PART of the filter: Hh[k] = (H[k] + conj(H[-k]))/2.
// For real x:  Re(ifft2(fft2(x)*H)) == ifft2(fft2(x)*Hh), and the operator
// x -> ifft2(fft2(x)*Hh) is a real linear map, so two real planes packed as
// z = x1 + i*x2 yield y1 = Re(T(z)), y2 = Im(T(z)).  This halves all
// workspace traffic. Hp lives in d_out (dead until pass 3 overwrites it).
__global__ __launch_bounds__(256) void permH(const float* __restrict__ Hr,
                                             const float* __restrict__ Hi,
                                             float2* __restrict__ Hp) {
    const int pw = blockIdx.x;
    const int kw = drev(pw);
    const int nw = (512 - kw) & 511;
    for (int ph = threadIdx.x; ph < 512; ph += 256) {
        const int kh = drev(ph);
        const int nh = (512 - kh) & 511;
        const float hr = 0.5f * (Hr[(kh << 9) + kw] + Hr[(nh << 9) + nw]);
        const float hi = 0.5f * (Hi[(kh << 9) + kw] - Hi[(nh << 9) + nw]);
        Hp[(pw << 9) + ph] = make_float2(hr, hi);
    }
}

// Pass 1: forward FFT along W. 4 waves/block, one row per wave.
// 64 complex planes: plane m packs real planes 2m (re) and 2m+1 (im).
__global__ __launch_bounds__(256) void pass1_rows(const float* __restrict__ x,
                                                  float2* __restrict__ ws) {
    __shared__ float2 smem[4 * 577];
    const int t = threadIdx.x;
    const int l = t & 63, w = t >> 6;
    float2* S = smem + w * 577;
    const size_t row = (size_t)blockIdx.x * 4 + w;   // 0..32767
    const size_t img = row >> 9;                     // 0..63
    const size_t h   = row & 511;
    const float* src1 = x + ((img * 2) << 18) + (h << 9);
    const float* src2 = src1 + (1 << 18);
    float2 v[8];
#pragma unroll
    for (int k = 0; k < 8; ++k) v[k] = make_float2(src1[l + 64*k], src2[l + 64*k]);
    fft512_fwd(v, S, l);
    float4* dst = (float4*)(ws + row * 512 + 8*l);   // 64B contiguous per lane
#pragma unroll
    for (int q = 0; q < 4; ++q)
        dst[q] = make_float4(v[2*q].x, v[2*q].y, v[2*q+1].x, v[2*q+1].y);
}

// Pass 2: 8 adjacent columns per block (512 thr = 8 waves), one column per
// wave. Coop line-complete staging; FFT scratch aliases the staging buffer.
__global__ __launch_bounds__(512) void pass2_cols(float2* __restrict__ ws,
                                                  const float2* __restrict__ Hp) {
    __shared__ float2 smem[4616];      // interleaved staging 9*511+7 <= 4606; 8 scratches of 577
    const int t = threadIdx.x;
    const int l = t & 63, w = t >> 6;  // wave id == column-in-tile
    const int img = blockIdx.x >> 6;   // 0..63 packed planes
    const int w0 = (blockIdx.x & 63) * 8;
    float2* base = ws + ((size_t)img << 18) + w0;

    {   // stage-in: 8 full 64B lines per wave-instruction
        const int c = t & 7, u = t >> 3;
#pragma unroll
        for (int k = 0; k < 8; ++k) {
            int h = u + 64*k;
            smem[9*h + c] = base[(size_t)h * 512 + c];
        }
    }
    __syncthreads();
    float2 v[8];
#pragma unroll
    for (int k = 0; k < 8; ++k) v[k] = smem[9*(l + 64*k) + w];
    __syncthreads();                   // staging dead; scratch may alias it
    float2* S = smem + w * 577;
    fft512_fwd(v, S, l);
    {   // filter: kh = drev(8l+q), kw = drev(w0+w) — pre-baked into Hp
        const float4* hp = (const float4*)(Hp + (((size_t)(w0 + w)) << 9) + 8*l);
#pragma unroll
        for (int q = 0; q < 4; ++q) {
            float4 h2 = hp[q];
            v[2*q]   = cmul(v[2*q],   make_float2(h2.x, h2.y));
            v[2*q+1] = cmul(v[2*q+1], make_float2(h2.z, h2.w));
        }
    }
    fft512_inv(v, S, l);
    __syncthreads();                   // all waves done with scratch
#pragma unroll
    for (int k = 0; k < 8; ++k) smem[9*(l + 64*k) + w] = v[k];
    __syncthreads();
    {   // stage-out, line-complete
        const int c = t & 7, u = t >> 3;
#pragma unroll
        for (int k = 0; k < 8; ++k) {
            int h = u + 64*k;
            base[(size_t)h * 512 + c] = smem[9*h + c];
        }
    }
}

// Pass 3: inverse FFT along W, scale 1/512^2; unpack Re -> plane 2m,
// Im -> plane 2m+1.
__global__ __launch_bounds__(256) void pass3_rows(const float2* __restrict__ ws,
                                                  float* __restrict__ out) {
    __shared__ float2 smem[4 * 577];
    const int t = threadIdx.x;
    const int l = t & 63, w = t >> 6;
    float2* S = smem + w * 577;
    const size_t row = (size_t)blockIdx.x * 4 + w;   // 0..32767
    const size_t img = row >> 9;                     // 0..63
    const size_t h   = row & 511;
    const float4* src = (const float4*)(ws + row * 512 + 8*l);
    float2 v[8];
#pragma unroll
    for (int q = 0; q < 4; ++q) {
        float4 p = src[q];
        v[2*q]   = make_float2(p.x, p.y);
        v[2*q+1] = make_float2(p.z, p.w);
    }
    fft512_inv(v, S, l);
    const float sc = 1.0f / (512.0f * 512.0f);
    float* dst1 = out + ((img * 2) << 18) + (h << 9);
    float* dst2 = dst1 + (1 << 18);
#pragma unroll
    for (int k = 0; k < 8; ++k) {
        dst1[l + 64*k] = v[k].x * sc;
        dst2[l + 64*k] = v[k].y * sc;
    }
}

extern "C" void kernel_launch(void* const* d_in, const int* in_sizes, int n_in,
                              void* d_out, int out_size, void* d_ws, size_t ws_size,
                              hipStream_t stream) {
    const float* x  = (const float*)d_in[0];   // [8,16,512,512]
    const float* Hr = (const float*)d_in[1];   // [512,512]
    const float* Hi = (const float*)d_in[2];   // [512,512]
    float* out = (float*)d_out;
    float2* ws = (float2*)d_ws;                // 128 MiB complex workspace (64 packed planes)
    float2* Hp = (float2*)d_out;               // 2 MiB of d_out reused as scratch;
                                               // pass 3 fully overwrites d_out after.

    permH<<<512, 256, 0, stream>>>(Hr, Hi, Hp);
    pass1_rows<<<8192, 256, 0, stream>>>(x, ws);
    pass2_cols<<<4096, 512, 0, stream>>>(ws, Hp);
    pass3_rows<<<8192, 256, 0, stream>>>(ws, out);
}

// Round 4
// 351.297 us; speedup vs baseline: 1.4174x; 1.0051x over previous
//
#include <hip/hip_runtime.h>

__device__ __forceinline__ float2 cmul(float2 a, float2 b) {
    return make_float2(a.x*b.x - a.y*b.y, a.x*b.y + a.y*b.x);
}
__device__ __forceinline__ float2 cadd(float2 a, float2 b){ return make_float2(a.x+b.x, a.y+b.y); }
__device__ __forceinline__ float2 csub(float2 a, float2 b){ return make_float2(a.x-b.x, a.y-b.y); }

// Wave-local LDS "barrier": all lane-exchange in the FFTs is within ONE wave
// (scratch regions are per-wave disjoint), so no s_barrier is needed.
// s_waitcnt lgkmcnt(0) makes the LDS write->read ordering architecturally
// explicit (1 SALU op, ~free since the DS writes are near-retired by then);
// the "memory" clobber stops compiler reordering across it.
__device__ __forceinline__ void wsync() {
    asm volatile("s_waitcnt lgkmcnt(0)" ::: "memory");
}

// multiply by (0, SGN): forward SGN=-1, inverse SGN=+1
template<int SGN> __device__ __forceinline__ float2 mul_i(float2 a) {
    return (SGN > 0) ? make_float2(-a.y, a.x) : make_float2(a.y, -a.x);
}
// W8^1 = (r, SGN*r), r = sqrt(0.5)
template<int SGN> __device__ __forceinline__ float2 mul_w81(float2 a) {
    const float r = 0.70710678118654752440f;
    return (SGN > 0) ? make_float2(r*(a.x - a.y), r*(a.x + a.y))
                     : make_float2(r*(a.x + a.y), r*(a.y - a.x));
}
// W8^3 = (-r, SGN*r)
template<int SGN> __device__ __forceinline__ float2 mul_w83(float2 a) {
    const float r = 0.70710678118654752440f;
    return (SGN > 0) ? make_float2(-r*(a.x + a.y), r*(a.x - a.y))
                     : make_float2(r*(a.y - a.x), -r*(a.x + a.y));
}

// 8-point DFT in registers, natural-order output: out[q] = sum_k in[k] W8^{SGN*qk}
template<int SGN>
__device__ __forceinline__ void bfly8(float2 v[8]) {
    float2 s0 = cadd(v[0], v[4]), d0 = csub(v[0], v[4]);
    float2 s1 = cadd(v[1], v[5]), d1 = csub(v[1], v[5]);
    float2 s2 = cadd(v[2], v[6]), d2 = csub(v[2], v[6]);
    float2 s3 = cadd(v[3], v[7]), d3 = csub(v[3], v[7]);
    d1 = mul_w81<SGN>(d1);
    d2 = mul_i<SGN>(d2);
    d3 = mul_w83<SGN>(d3);
    float2 p0 = cadd(s0, s2), q0 = csub(s0, s2);
    float2 p1 = cadd(s1, s3), q1 = mul_i<SGN>(csub(s1, s3));
    float2 P0 = cadd(d0, d2), Q0 = csub(d0, d2);
    float2 P1 = cadd(d1, d3), Q1 = mul_i<SGN>(csub(d1, d3));
    v[0] = cadd(p0, p1);
    v[4] = csub(p0, p1);
    v[2] = cadd(q0, q1);
    v[6] = csub(q0, q1);
    v[1] = cadd(P0, P1);
    v[5] = csub(P0, P1);
    v[3] = cadd(Q0, Q1);
    v[7] = csub(Q0, Q1);
}

// v[q] *= W^{SGN*q}, W = cis(2*pi*frac)
template<int SGN>
__device__ __forceinline__ void twiddle7(float2 v[8], float frac) {
    const float ang = (SGN > 0 ? 6.2831853071795864769f : -6.2831853071795864769f) * frac;
    float sn, cs; __sincosf(ang, &sn, &cs);
    const float2 w1 = make_float2(cs, sn);
    float2 w = w1;
    v[1] = cmul(v[1], w);
#pragma unroll
    for (int q = 2; q < 8; ++q) { w = cmul(w, w1); v[q] = cmul(v[q], w); }
}

// Swizzles for the two LDS exchanges (both uniform 4 accesses/bank for b64):
//   f1(a) = a + 2*(a>>6)  (exchange stride-64 <-> stride-8 pattern)
//   f2(a) = a + (a>>3)    (exchange stride-8  <-> contiguous pattern)

// Forward 512-pt FFT, one wave, lane l (0..63), v preloaded with h = l+64k.
// Output: v[q] = spectrum value at position p = 8l+q (freq = octal-digit-rev(p)).
// S: per-wave scratch, >= 575 float2. Wave-local sync only -- no block barriers.
__device__ __forceinline__ void fft512_fwd(float2 v[8], float2* S, int l) {
    const int g = l >> 3, j = l & 7;
    bfly8<-1>(v);
    twiddle7<-1>(v, (float)l * (1.0f/512.0f));
#pragma unroll
    for (int q = 0; q < 8; ++q) S[66*q + l] = v[q];          // f1(64q+l)
    wsync();
#pragma unroll
    for (int k = 0; k < 8; ++k) v[k] = S[66*g + j + 8*k];    // f1(64g+j+8k)
    bfly8<-1>(v);
    twiddle7<-1>(v, (float)j * (1.0f/64.0f));
#pragma unroll
    for (int q = 0; q < 8; ++q) S[72*g + 9*q + j] = v[q];    // f2(64g+8q+j)
    wsync();
#pragma unroll
    for (int k = 0; k < 8; ++k) v[k] = S[9*l + k];           // f2(8l+k)
    bfly8<-1>(v);
}

// Inverse (unscaled, x512): input v[q] = value at position 8l+q, output
// v[k] = natural-order sample at h = l+64k. Exact mirror of fft512_fwd.
__device__ __forceinline__ void fft512_inv(float2 v[8], float2* S, int l) {
    const int g = l >> 3, j = l & 7;
    bfly8<1>(v);
#pragma unroll
    for (int k = 0; k < 8; ++k) S[9*l + k] = v[k];
    wsync();
#pragma unroll
    for (int q = 0; q < 8; ++q) v[q] = S[72*g + 9*q + j];
    twiddle7<1>(v, (float)j * (1.0f/64.0f));
    bfly8<1>(v);
#pragma unroll
    for (int k = 0; k < 8; ++k) S[66*g + j + 8*k] = v[k];
    wsync();
#pragma unroll
    for (int q = 0; q < 8; ++q) v[q] = S[66*q + l];
    twiddle7<1>(v, (float)l * (1.0f/512.0f));
    bfly8<1>(v);
}

__device__ __forceinline__ int drev(int x) {   // reverse 3 octal digits of 9-bit x
    return ((x & 7) << 6) | (x & 56) | (x >> 6);
}

// Prologue: Hp[pw*512 + ph] = Hh[drev(ph)][drev(pw)] where Hh is the
// HERMITIAN PART of the filter: Hh[k] = (H[k] + conj(H[-k]))/2.
// For real x:  Re(ifft2(fft2(x)*H)) == ifft2(fft2(x)*Hh), and the operator
// x -> ifft2(fft2(x)*Hh) is a real linear map, so two real planes packed as
// z = x1 + i*x2 yield y1 = Re(T(z)), y2 = Im(T(z)).  This halves all
// workspace traffic. Hp lives in d_out (dead until pass 3 overwrites it).
__global__ __launch_bounds__(256) void permH(const float* __restrict__ Hr,
                                             const float* __restrict__ Hi,
                                             float2* __restrict__ Hp) {
    const int pw = blockIdx.x;
    const int kw = drev(pw);
    const int nw = (512 - kw) & 511;
    for (int ph = threadIdx.x; ph < 512; ph += 256) {
        const int kh = drev(ph);
        const int nh = (512 - kh) & 511;
        const float hr = 0.5f * (Hr[(kh << 9) + kw] + Hr[(nh << 9) + nw]);
        const float hi = 0.5f * (Hi[(kh << 9) + kw] - Hi[(nh << 9) + nw]);
        Hp[(pw << 9) + ph] = make_float2(hr, hi);
    }
}

// Pass 1: forward FFT along W. 4 waves/block, one row per wave.
// 64 complex planes: plane m packs real planes 2m (re) and 2m+1 (im).
// No block barriers -- waves run fully decoupled.
__global__ __launch_bounds__(256) void pass1_rows(const float* __restrict__ x,
                                                  float2* __restrict__ ws) {
    __shared__ float2 smem[4 * 577];
    const int t = threadIdx.x;
    const int l = t & 63, w = t >> 6;
    float2* S = smem + w * 577;
    const size_t row = (size_t)blockIdx.x * 4 + w;   // 0..32767
    const size_t img = row >> 9;                     // 0..63
    const size_t h   = row & 511;
    const float* src1 = x + ((img * 2) << 18) + (h << 9);
    const float* src2 = src1 + (1 << 18);
    float2 v[8];
#pragma unroll
    for (int k = 0; k < 8; ++k) v[k] = make_float2(src1[l + 64*k], src2[l + 64*k]);
    fft512_fwd(v, S, l);
    float4* dst = (float4*)(ws + row * 512 + 8*l);   // 64B contiguous per lane
#pragma unroll
    for (int q = 0; q < 4; ++q)
        dst[q] = make_float4(v[2*q].x, v[2*q].y, v[2*q+1].x, v[2*q+1].y);
}

// Pass 2: 8 adjacent columns per block (512 thr = 8 waves), one column per
// wave. Coop line-complete staging (float4, 16B/lane); FFT scratch aliases
// the staging buffer. 4 block barriers (staging hazards only); FFT-internal
// sync is wave-local.
__global__ __launch_bounds__(512) void pass2_cols(float2* __restrict__ ws,
                                                  const float2* __restrict__ Hp) {
    __shared__ float2 smem[4616];      // interleaved staging 9*511+7 <= 4606; 8 scratches of 577
    const int t = threadIdx.x;
    const int l = t & 63, w = t >> 6;  // wave id == column-in-tile
    const int img = blockIdx.x >> 6;   // 0..63 packed planes
    const int w0 = (blockIdx.x & 63) * 8;
    float2* base = ws + ((size_t)img << 18) + w0;

    {   // stage-in: float4 per lane (2 adjacent columns), line-complete
        const int c = t & 3, u = t >> 2;       // c: column pair, u: 0..127
#pragma unroll
        for (int k = 0; k < 4; ++k) {
            int h = u + 128*k;
            float4 p = *(const float4*)(base + (size_t)h * 512 + 2*c);
            smem[9*h + 2*c]     = make_float2(p.x, p.y);
            smem[9*h + 2*c + 1] = make_float2(p.z, p.w);
        }
    }
    __syncthreads();
    float2 v[8];
#pragma unroll
    for (int k = 0; k < 8; ++k) v[k] = smem[9*(l + 64*k) + w];
    __syncthreads();                   // staging dead; scratch may alias it
    float2* S = smem + w * 577;
    fft512_fwd(v, S, l);
    {   // filter: kh = drev(8l+q), kw = drev(w0+w) — pre-baked into Hp
        const float4* hp = (const float4*)(Hp + (((size_t)(w0 + w)) << 9) + 8*l);
#pragma unroll
        for (int q = 0; q < 4; ++q) {
            float4 h2 = hp[q];
            v[2*q]   = cmul(v[2*q],   make_float2(h2.x, h2.y));
            v[2*q+1] = cmul(v[2*q+1], make_float2(h2.z, h2.w));
        }
    }
    fft512_inv(v, S, l);
    __syncthreads();                   // all waves done with scratch
#pragma unroll
    for (int k = 0; k < 8; ++k) smem[9*(l + 64*k) + w] = v[k];
    __syncthreads();
    {   // stage-out, float4 per lane, line-complete
        const int c = t & 3, u = t >> 2;
#pragma unroll
        for (int k = 0; k < 4; ++k) {
            int h = u + 128*k;
            float2 a = smem[9*h + 2*c], b = smem[9*h + 2*c + 1];
            *(float4*)(base + (size_t)h * 512 + 2*c) = make_float4(a.x, a.y, b.x, b.y);
        }
    }
}

// Pass 3: inverse FFT along W, scale 1/512^2; unpack Re -> plane 2m,
// Im -> plane 2m+1. No block barriers.
__global__ __launch_bounds__(256) void pass3_rows(const float2* __restrict__ ws,
                                                  float* __restrict__ out) {
    __shared__ float2 smem[4 * 577];
    const int t = threadIdx.x;
    const int l = t & 63, w = t >> 6;
    float2* S = smem + w * 577;
    const size_t row = (size_t)blockIdx.x * 4 + w;   // 0..32767
    const size_t img = row >> 9;                     // 0..63
    const size_t h   = row & 511;
    const float4* src = (const float4*)(ws + row * 512 + 8*l);
    float2 v[8];
#pragma unroll
    for (int q = 0; q < 4; ++q) {
        float4 p = src[q];
        v[2*q]   = make_float2(p.x, p.y);
        v[2*q+1] = make_float2(p.z, p.w);
    }
    fft512_inv(v, S, l);
    const float sc = 1.0f / (512.0f * 512.0f);
    float* dst1 = out + ((img * 2) << 18) + (h << 9);
    float* dst2 = dst1 + (1 << 18);
#pragma unroll
    for (int k = 0; k < 8; ++k) {
        dst1[l + 64*k] = v[k].x * sc;
        dst2[l + 64*k] = v[k].y * sc;
    }
}

extern "C" void kernel_launch(void* const* d_in, const int* in_sizes, int n_in,
                              void* d_out, int out_size, void* d_ws, size_t ws_size,
                              hipStream_t stream) {
    const float* x  = (const float*)d_in[0];   // [8,16,512,512]
    const float* Hr = (const float*)d_in[1];   // [512,512]
    const float* Hi = (const float*)d_in[2];   // [512,512]
    float* out = (float*)d_out;
    float2* ws = (float2*)d_ws;                // 128 MiB complex workspace (64 packed planes)
    float2* Hp = (float2*)d_out;               // 2 MiB of d_out reused as scratch;
                                               // pass 3 fully overwrites d_out after.

    permH<<<512, 256, 0, stream>>>(Hr, Hi, Hp);
    pass1_rows<<<8192, 256, 0, stream>>>(x, ws);
    pass2_cols<<<4096, 512, 0, stream>>>(ws, Hp);
    pass3_rows<<<8192, 256, 0, stream>>>(ws, out);
}